// Round 5
// baseline (494.811 us; speedup 1.0000x reference)
//
#include <hip/hip_runtime.h>
#include <hip/hip_bf16.h>

typedef __bf16 bf16x8 __attribute__((ext_vector_type(8)));
typedef float f32x4 __attribute__((ext_vector_type(4)));

#define D_FEAT 128
#define LDS_STRIDE 136   // 128 + 8 pad; row stride 272 B keeps 16B alignment

// ---------- dtype probe ----------
// Even u16s of x. bf16 data -> elements 0,2,..: N(0,1) bf16 exponents, 64/64 in
// [100,140]. fp32 data (little-endian) -> LOW mantissa halves, ~uniform -> ~10/64.
__global__ void probe_kernel(const void* x, int* flags) {
    if (threadIdx.x < 64) {
        const unsigned short* u = (const unsigned short*)x;
        unsigned short v = u[threadIdx.x * 2];
        int e = (v >> 7) & 0xFF;
        bool plaus = (e >= 100 && e <= 140);
        unsigned long long m = __ballot(plaus);
        if (threadIdx.x == 0) {
            flags[0] = (__popcll(m) >= 48) ? 1 : 0;  // 1: tensors bf16, 0: fp32
            flags[1] = 1;                            // h (internal) is always bf16
        }
    }
}

__device__ __forceinline__ float ld(const void* p, int is16, size_t i) {
    return is16 ? (float)((const __hip_bfloat16*)p)[i] : ((const float*)p)[i];
}

// ---------- weight pack: convert all weights/biases to bf16 in ws ----------
// layout (u16 elems): W1l@0 [16384] W1r@16384 [16384] W2l@32768 [8192]
//                     W2r@40960 [8192] b1@49152 [128] b2@49280 [64]
__global__ void prep_kernel(const void* W1l, const void* b1, const void* W1r,
                            const void* W2l, const void* b2, const void* W2r,
                            const int* __restrict__ flags, unsigned short* wout) {
    const int is16 = flags[0];
    const void* srcs[6] = {W1l, W1r, W2l, W2r, b1, b2};
    const int  sizes[6] = {16384, 16384, 8192, 8192, 128, 64};
    int base = 0;
    for (int s = 0; s < 6; ++s) {
        for (int i = threadIdx.x; i < sizes[s]; i += blockDim.x) {
            __hip_bfloat16 hb = (__hip_bfloat16)ld(srcs[s], is16, i);
            wout[base + i] = *(const unsigned short*)&hb;
        }
        base += sizes[s];
    }
}

// ---------- CSR construction (validated by R2==R3 bit-identity) ----------
__global__ void count_deg_kernel(const int* __restrict__ dst, int* __restrict__ deg, int E) {
    int i = blockIdx.x * blockDim.x + threadIdx.x;
    if (i < E) atomicAdd(&deg[dst[i]], 1);
}

__global__ void scan_kernel(const int* __restrict__ deg, int* __restrict__ off,
                            int* __restrict__ cursor, int n) {
    __shared__ int wsum[4];
    __shared__ int carry_s;
    const int lane = threadIdx.x & 63;
    const int wv = threadIdx.x >> 6;
    if (threadIdx.x == 0) carry_s = 0;
    __syncthreads();
    for (int base = 0; base < n; base += 1024) {
        int carry = carry_s;
        int i0 = base + threadIdx.x * 4;
        int v0 = (i0 + 0 < n) ? deg[i0 + 0] : 0;
        int v1 = (i0 + 1 < n) ? deg[i0 + 1] : 0;
        int v2 = (i0 + 2 < n) ? deg[i0 + 2] : 0;
        int v3 = (i0 + 3 < n) ? deg[i0 + 3] : 0;
        int tsum = v0 + v1 + v2 + v3;
        int sc = tsum;
        #pragma unroll
        for (int s = 1; s < 64; s <<= 1) {
            int t = __shfl_up(sc, s, 64);
            if (lane >= s) sc += t;
        }
        if (lane == 63) wsum[wv] = sc;
        __syncthreads();
        int woff = 0;
        for (int w = 0; w < wv; ++w) woff += wsum[w];
        int p = carry + woff + (sc - tsum);
        if (i0 + 0 < n) { off[i0 + 0] = p; cursor[i0 + 0] = p; p += v0; }
        if (i0 + 1 < n) { off[i0 + 1] = p; cursor[i0 + 1] = p; p += v1; }
        if (i0 + 2 < n) { off[i0 + 2] = p; cursor[i0 + 2] = p; p += v2; }
        if (i0 + 3 < n) { off[i0 + 3] = p; cursor[i0 + 3] = p; p += v3; }
        __syncthreads();
        if (threadIdx.x == 0) carry_s = carry + wsum[0] + wsum[1] + wsum[2] + wsum[3];
        __syncthreads();
    }
}

__global__ void fill_kernel(const int* __restrict__ src, const int* __restrict__ dst,
                            int* __restrict__ cursor, int* __restrict__ esrc, int E) {
    int i = blockIdx.x * blockDim.x + threadIdx.x;
    if (i < E) {
        int p = atomicAdd(&cursor[dst[i]], 1);
        esrc[p] = src[i];
    }
}

// ---------- fused layer: mean-agg (LDS) + dual GEMM via MFMA ----------
// out[node] = act(mean_nb @ Wl^T + bias + self @ Wr^T), 64 nodes/block.
// oflag[0]==1 -> write bf16, ==0 -> write fp32.
template <int NOUT, bool RELU>
__global__ __launch_bounds__(256)
void fused_layer_kernel(const void* feat, const int* __restrict__ flagp,
                        const int* __restrict__ off, const int* __restrict__ deg,
                        const int* __restrict__ esrc,
                        const unsigned short* __restrict__ Wl,
                        const unsigned short* __restrict__ Wr,
                        const unsigned short* __restrict__ bias,
                        const int* __restrict__ oflag,
                        void* __restrict__ out, int N) {
    __shared__ __hip_bfloat16 meanT[64][LDS_STRIDE];
    __shared__ __hip_bfloat16 selfT[64][LDS_STRIDE];
    const int tid = threadIdx.x;
    const int is16 = flagp[0];           // wave-uniform
    const int o16 = oflag[0];
    const int node0 = blockIdx.x * 64;

    // phase 1a: stage self rows (64 x 128) into LDS as bf16
    if (is16) {
        const __hip_bfloat16* f16 = (const __hip_bfloat16*)feat;
        #pragma unroll
        for (int rep = 0; rep < 4; ++rep) {
            int c = rep * 256 + tid;
            int row = c >> 4, kc = (c & 15) * 8;
            int g = node0 + row; if (g > N - 1) g = N - 1;
            *(bf16x8*)&selfT[row][kc] = *(const bf16x8*)(f16 + (size_t)g * D_FEAT + kc);
        }
    } else {
        const float* fp = (const float*)feat;
        #pragma unroll
        for (int rep = 0; rep < 4; ++rep) {
            int c = rep * 256 + tid;
            int row = c >> 4, kc = (c & 15) * 8;
            int g = node0 + row; if (g > N - 1) g = N - 1;
            const float* p = fp + (size_t)g * D_FEAT + kc;
            union { bf16x8 v; __hip_bfloat16 h[8]; } t;
            #pragma unroll
            for (int j = 0; j < 8; ++j) t.h[j] = (__hip_bfloat16)p[j];
            *(bf16x8*)&selfT[row][kc] = t.v;
        }
    }

    // phase 1b: mean aggregation. Thread (half,f): feature f of 32 nodes.
    // Wave-uniform node -> uniform trip count, coalesced feature rows.
    const int f = tid & 127;
    const int half = tid >> 7;
    for (int nl = half * 32; nl < half * 32 + 32; ++nl) {
        int g = node0 + nl;
        float acc = 0.f;
        int d = 0;
        if (g < N) {
            int st = off[g];
            d = deg[g];
            int j = 0;
            if (is16) {
                const __hip_bfloat16* f16 = (const __hip_bfloat16*)feat;
                for (; j + 4 <= d; j += 4) {
                    int s0 = esrc[st + j], s1 = esrc[st + j + 1];
                    int s2 = esrc[st + j + 2], s3 = esrc[st + j + 3];
                    acc += (float)f16[(size_t)s0 * D_FEAT + f]
                         + (float)f16[(size_t)s1 * D_FEAT + f]
                         + (float)f16[(size_t)s2 * D_FEAT + f]
                         + (float)f16[(size_t)s3 * D_FEAT + f];
                }
                for (; j < d; ++j)
                    acc += (float)f16[(size_t)esrc[st + j] * D_FEAT + f];
            } else {
                const float* fp = (const float*)feat;
                for (; j + 4 <= d; j += 4) {
                    int s0 = esrc[st + j], s1 = esrc[st + j + 1];
                    int s2 = esrc[st + j + 2], s3 = esrc[st + j + 3];
                    acc += fp[(size_t)s0 * D_FEAT + f] + fp[(size_t)s1 * D_FEAT + f]
                         + fp[(size_t)s2 * D_FEAT + f] + fp[(size_t)s3 * D_FEAT + f];
                }
                for (; j < d; ++j)
                    acc += fp[(size_t)esrc[st + j] * D_FEAT + f];
            }
        }
        meanT[nl][f] = (__hip_bfloat16)(acc / (float)(d > 0 ? d : 1));
    }
    __syncthreads();

    // phase 2: dual GEMM, wave w -> rows w*16..w*16+15 x NOUT.
    const int lane = tid & 63;
    const int wave = tid >> 6;
    const int lrow = lane & 15;
    const int kg = lane >> 4;
    constexpr int NT = NOUT / 16;
    f32x4 acc[NT];
    #pragma unroll
    for (int t = 0; t < NT; ++t) acc[t] = (f32x4){0.f, 0.f, 0.f, 0.f};

    const int arow = wave * 16 + lrow;
    #pragma unroll
    for (int hh = 0; hh < 2; ++hh) {
        const __hip_bfloat16* At = hh ? &selfT[0][0] : &meanT[0][0];
        const unsigned short* W = hh ? Wr : Wl;
        #pragma unroll
        for (int ks = 0; ks < 4; ++ks) {
            const int k0 = ks * 32 + kg * 8;
            bf16x8 a = *(const bf16x8*)(At + arow * LDS_STRIDE + k0);
            #pragma unroll
            for (int t = 0; t < NT; ++t) {
                int n = t * 16 + lrow;
                bf16x8 b = *(const bf16x8*)(W + (size_t)n * D_FEAT + k0);
                acc[t] = __builtin_amdgcn_mfma_f32_16x16x32_bf16(a, b, acc[t], 0, 0, 0);
            }
        }
    }
    // C/D layout: col = lane&15, row = (lane>>4)*4 + reg  [m89/m91]
    const int orow0 = node0 + wave * 16 + kg * 4;
    #pragma unroll
    for (int t = 0; t < NT; ++t) {
        const int col = t * 16 + lrow;
        float bv = (float)(*(const __hip_bfloat16*)&bias[col]);
        #pragma unroll
        for (int r = 0; r < 4; ++r) {
            int orow = orow0 + r;
            if (orow < N) {
                float v = acc[t][r] + bv;
                if (RELU) v = fmaxf(v, 0.f);
                if (o16) ((__hip_bfloat16*)out)[(size_t)orow * NOUT + col] = (__hip_bfloat16)v;
                else     ((float*)out)[(size_t)orow * NOUT + col] = v;
            }
        }
    }
}

// ---------- launch ----------
extern "C" void kernel_launch(void* const* d_in, const int* in_sizes, int n_in,
                              void* d_out, int out_size, void* d_ws, size_t ws_size,
                              hipStream_t stream) {
    const void* x   = d_in[0];
    const int* eidx = (const int*)d_in[1];
    const void* W1l = d_in[2];
    const void* b1  = d_in[3];
    const void* W1r = d_in[4];
    const void* W2l = d_in[5];
    const void* b2  = d_in[6];
    const void* W2r = d_in[7];

    const int N = in_sizes[0] / D_FEAT;   // 50000
    const int E = in_sizes[1] / 2;        // 600000
    const int* src = eidx;                // reference layout: [2, E] row-major
    const int* dst = eidx + E;

    char* ws = (char*)d_ws;
    size_t o = 0;
    auto alloc = [&](size_t bytes) -> void* {
        void* p = ws + o;
        o += (bytes + 255) & ~(size_t)255;
        return p;
    };
    int* flags  = (int*)alloc(256);
    int* deg    = (int*)alloc((size_t)N * 4);
    int* off    = (int*)alloc((size_t)N * 4);
    int* cursor = (int*)alloc((size_t)N * 4);
    int* esrc   = (int*)alloc((size_t)E * 4);
    unsigned short* wconv = (unsigned short*)alloc(49344 * 2);
    __hip_bfloat16* h = (__hip_bfloat16*)alloc((size_t)N * D_FEAT * 2);
    (void)ws_size; (void)n_in; (void)out_size;
    // peak ws ~= 15.4 MB (R3 proved >= 25.9 MB available)

    probe_kernel<<<1, 64, 0, stream>>>(x, flags);
    prep_kernel<<<1, 256, 0, stream>>>(W1l, b1, W1r, W2l, b2, W2r, flags, wconv);
    hipMemsetAsync(deg, 0, (size_t)N * 4, stream);
    count_deg_kernel<<<(E + 255) / 256, 256, 0, stream>>>(dst, deg, E);
    scan_kernel<<<1, 256, 0, stream>>>(deg, off, cursor, N);
    fill_kernel<<<(E + 255) / 256, 256, 0, stream>>>(src, dst, cursor, esrc, E);

    const int nblocks = (N + 63) / 64;
    // layer 1: h = relu(sage(x)); h always bf16 (flags[1]==1)
    fused_layer_kernel<128, true><<<nblocks, 256, 0, stream>>>(
        x, flags + 0, off, deg, esrc,
        wconv + 0, wconv + 16384, wconv + 49152, flags + 1, h, N);
    // layer 2: out = sage(h); output width matches input dtype scenario
    fused_layer_kernel<64, false><<<nblocks, 256, 0, stream>>>(
        h, flags + 1, off, deg, esrc,
        wconv + 32768, wconv + 40960, wconv + 49280, flags + 0, d_out, N);
}

// Round 6
// 402.164 us; speedup vs baseline: 1.2304x; 1.2304x over previous
//
#include <hip/hip_runtime.h>
#include <hip/hip_bf16.h>

typedef __bf16 bf16x8 __attribute__((ext_vector_type(8)));
typedef float f32x4 __attribute__((ext_vector_type(4)));

#define D_FEAT 128
#define MT_STRIDE 136   // 128 + 8 pad (ushort units); row stride 272 B, 16B-aligned

__device__ __forceinline__ float bf16_to_f(unsigned int u16) {
    union { unsigned int i; float f; } c; c.i = u16 << 16; return c.f;
}
__device__ __forceinline__ unsigned short f_to_bf16(float f) {
    __hip_bfloat16 h = (__hip_bfloat16)f;
    return *(unsigned short*)&h;
}
__device__ __forceinline__ float ld(const void* p, int is16, size_t i) {
    return is16 ? (float)((const __hip_bfloat16*)p)[i] : ((const float*)p)[i];
}

// ---------- dtype probe (proven R5) ----------
__global__ void probe_kernel(const void* x, int* flags) {
    if (threadIdx.x < 64) {
        const unsigned short* u = (const unsigned short*)x;
        unsigned short v = u[threadIdx.x * 2];
        int e = (v >> 7) & 0xFF;
        bool plaus = (e >= 100 && e <= 140);
        unsigned long long m = __ballot(plaus);
        if (threadIdx.x == 0) {
            flags[0] = (__popcll(m) >= 48) ? 1 : 0;  // 1: tensors bf16, 0: fp32
            flags[1] = 1;                            // internal h is always bf16
        }
    }
}

// ---------- weight pack -> bf16 (proven R5) ----------
__global__ void prep_kernel(const void* W1l, const void* b1, const void* W1r,
                            const void* W2l, const void* b2, const void* W2r,
                            const int* __restrict__ flags, unsigned short* wout) {
    const int is16 = flags[0];
    const void* srcs[6] = {W1l, W1r, W2l, W2r, b1, b2};
    const int  sizes[6] = {16384, 16384, 8192, 8192, 128, 64};
    int base = 0;
    for (int s = 0; s < 6; ++s) {
        for (int i = threadIdx.x; i < sizes[s]; i += blockDim.x)
            wout[base + i] = f_to_bf16(ld(srcs[s], is16, i));
        base += sizes[s];
    }
}

// ---------- x -> bf16 conversion (or copy) ----------
__global__ void conv_kernel(const void* x, const int* __restrict__ flags,
                            unsigned short* __restrict__ xb, int n4) {
    int i = blockIdx.x * blockDim.x + threadIdx.x;
    if (i >= n4) return;
    if (flags[0]) {
        ((uint2*)xb)[i] = ((const uint2*)x)[i];      // already bf16: copy 4 elems
    } else {
        const float4 v = ((const float4*)x)[i];
        union { unsigned short us[4]; uint2 u; } t;
        t.us[0] = f_to_bf16(v.x); t.us[1] = f_to_bf16(v.y);
        t.us[2] = f_to_bf16(v.z); t.us[3] = f_to_bf16(v.w);
        ((uint2*)xb)[i] = t.u;
    }
}

// ---------- CSR construction (proven R2/R3/R5) ----------
__global__ void count_deg_kernel(const int* __restrict__ dst, int* __restrict__ deg, int E) {
    int i = blockIdx.x * blockDim.x + threadIdx.x;
    if (i < E) atomicAdd(&deg[dst[i]], 1);
}

__global__ void scan_kernel(const int* __restrict__ deg, int* __restrict__ off,
                            int* __restrict__ cursor, int n) {
    __shared__ int wsum[4];
    __shared__ int carry_s;
    const int lane = threadIdx.x & 63;
    const int wv = threadIdx.x >> 6;
    if (threadIdx.x == 0) carry_s = 0;
    __syncthreads();
    for (int base = 0; base < n; base += 1024) {
        int carry = carry_s;
        int i0 = base + threadIdx.x * 4;
        int v0 = (i0 + 0 < n) ? deg[i0 + 0] : 0;
        int v1 = (i0 + 1 < n) ? deg[i0 + 1] : 0;
        int v2 = (i0 + 2 < n) ? deg[i0 + 2] : 0;
        int v3 = (i0 + 3 < n) ? deg[i0 + 3] : 0;
        int tsum = v0 + v1 + v2 + v3;
        int sc = tsum;
        #pragma unroll
        for (int s = 1; s < 64; s <<= 1) {
            int t = __shfl_up(sc, s, 64);
            if (lane >= s) sc += t;
        }
        if (lane == 63) wsum[wv] = sc;
        __syncthreads();
        int woff = 0;
        for (int w = 0; w < wv; ++w) woff += wsum[w];
        int p = carry + woff + (sc - tsum);
        if (i0 + 0 < n) { off[i0 + 0] = p; cursor[i0 + 0] = p; p += v0; }
        if (i0 + 1 < n) { off[i0 + 1] = p; cursor[i0 + 1] = p; p += v1; }
        if (i0 + 2 < n) { off[i0 + 2] = p; cursor[i0 + 2] = p; p += v2; }
        if (i0 + 3 < n) { off[i0 + 3] = p; cursor[i0 + 3] = p; p += v3; }
        __syncthreads();
        if (threadIdx.x == 0) carry_s = carry + wsum[0] + wsum[1] + wsum[2] + wsum[3];
        __syncthreads();
    }
    if (threadIdx.x == 0) off[n] = carry_s;   // sentinel: off[N] = E
}

__global__ void fill_kernel(const int* __restrict__ src, const int* __restrict__ dst,
                            int* __restrict__ cursor, int* __restrict__ esrc, int E) {
    int i = blockIdx.x * blockDim.x + threadIdx.x;
    if (i < E) {
        int p = atomicAdd(&cursor[dst[i]], 1);
        esrc[p] = src[i];
    }
}

// ---------- fused layer: streaming CSR mean-agg + dual MFMA GEMM ----------
// 64 nodes/block, 4 waves; wave w owns nodes [n_lo, n_lo+16) = one contiguous
// CSR edge segment. Edge stream 4-wide (4 indep row loads in flight), wave-
// uniform boundary flushes into wave-private meanT rows. NO __syncthreads.
template <int NOUT, bool RELU>
__global__ __launch_bounds__(256)
void fused_layer_kernel(const void* feat, const int* __restrict__ flagp,
                        const int* __restrict__ off, const int* __restrict__ esrc,
                        const unsigned short* __restrict__ Wl,
                        const unsigned short* __restrict__ Wr,
                        const unsigned short* __restrict__ bias,
                        const int* __restrict__ oflag,
                        void* __restrict__ out, int N) {
    __shared__ unsigned short meanT[64][MT_STRIDE];
    const int tid = threadIdx.x;
    const int lane = tid & 63;
    const int wave = tid >> 6;
    const int is16 = flagp[0];     // wave-uniform
    const int o16 = oflag[0];
    const int node0 = blockIdx.x * 64;
    const int n_lo = node0 + wave * 16;

    if (n_lo < N) {
        const int n_hi_c = min(n_lo + 16, N);
        // preload the wave's 17 offsets into lanes 0..16; fetch via shfl
        int offv = off[min(n_lo + min(lane, 16), N)];
        #define OFFAT(i) __shfl(offv, (i), 64)
        const int e_end = OFFAT(n_hi_c - n_lo);
        int e = OFFAT(0);
        int g = n_lo;
        int gstart = e;
        int gend = OFFAT(1);
        float ax = 0.f, ay = 0.f;   // lane accumulates features 2*lane, 2*lane+1
        for (; e < e_end; e += 4) {
            int sk[4];
            #pragma unroll
            for (int k = 0; k < 4; ++k) sk[k] = esrc[min(e + k, e_end - 1)];
            float rx[4], ry[4];
            if (is16) {
                #pragma unroll
                for (int k = 0; k < 4; ++k) {
                    unsigned int u = ((const unsigned int*)
                        ((const unsigned short*)feat + (size_t)sk[k] * D_FEAT))[lane];
                    rx[k] = bf16_to_f(u & 0xffffu);
                    ry[k] = bf16_to_f(u >> 16);
                }
            } else {
                #pragma unroll
                for (int k = 0; k < 4; ++k) {
                    float2 v = ((const float2*)
                        ((const float*)feat + (size_t)sk[k] * D_FEAT))[lane];
                    rx[k] = v.x; ry[k] = v.y;
                }
            }
            #pragma unroll
            for (int k = 0; k < 4; ++k) {
                if (e + k < e_end) {
                    while (e + k >= gend) {   // wave-uniform flush of node g
                        int d = gend - gstart;
                        float inv = 1.f / (float)(d > 0 ? d : 1);
                        unsigned int pk = (unsigned int)f_to_bf16(ax * inv)
                                        | ((unsigned int)f_to_bf16(ay * inv) << 16);
                        *(unsigned int*)&meanT[g - node0][lane * 2] = pk;
                        ax = ay = 0.f;
                        ++g; gstart = gend;
                        gend = OFFAT(min(g - n_lo + 1, 16));
                    }
                    ax += rx[k]; ay += ry[k];
                }
            }
        }
        while (g < n_hi_c) {   // tail flush (incl. trailing zero-degree nodes)
            int d = gend - gstart;
            float inv = 1.f / (float)(d > 0 ? d : 1);
            unsigned int pk = (unsigned int)f_to_bf16(ax * inv)
                            | ((unsigned int)f_to_bf16(ay * inv) << 16);
            *(unsigned int*)&meanT[g - node0][lane * 2] = pk;
            ax = ay = 0.f;
            ++g; gstart = gend;
            gend = OFFAT(min(g - n_lo + 1, 16));
        }
        #undef OFFAT
    }

    // phase 2: dual GEMM on this wave's 16 rows (wave-private meanT -> no barrier)
    const int lrow = lane & 15;
    const int kg = lane >> 4;
    constexpr int NT = NOUT / 16;
    f32x4 acc[NT];
    #pragma unroll
    for (int t = 0; t < NT; ++t) acc[t] = (f32x4){0.f, 0.f, 0.f, 0.f};

    const int grow = min(n_lo + lrow, N - 1);
    #pragma unroll
    for (int hh = 0; hh < 2; ++hh) {
        const unsigned short* W = hh ? Wr : Wl;
        #pragma unroll
        for (int ks = 0; ks < 4; ++ks) {
            const int k0 = ks * 32 + kg * 8;
            bf16x8 a;
            if (hh == 0) {
                a = *(const bf16x8*)&meanT[wave * 16 + lrow][k0];
            } else if (is16) {
                a = *(const bf16x8*)((const unsigned short*)feat + (size_t)grow * D_FEAT + k0);
            } else {
                const float* fp = (const float*)feat + (size_t)grow * D_FEAT + k0;
                union { bf16x8 v; unsigned short us[8]; } t;
                #pragma unroll
                for (int j = 0; j < 8; ++j) t.us[j] = f_to_bf16(fp[j]);
                a = t.v;
            }
            #pragma unroll
            for (int t = 0; t < NT; ++t) {
                bf16x8 b = *(const bf16x8*)(W + (size_t)(t * 16 + lrow) * D_FEAT + k0);
                acc[t] = __builtin_amdgcn_mfma_f32_16x16x32_bf16(a, b, acc[t], 0, 0, 0);
            }
        }
    }
    // C/D layout: col = lane&15, row = (lane>>4)*4 + reg  [m89/m91]
    const int orow0 = n_lo + kg * 4;
    #pragma unroll
    for (int t = 0; t < NT; ++t) {
        const int col = t * 16 + lrow;
        float bv = bf16_to_f(bias[col]);
        #pragma unroll
        for (int r = 0; r < 4; ++r) {
            int orow = orow0 + r;
            if (orow < N) {
                float v = acc[t][r] + bv;
                if (RELU) v = fmaxf(v, 0.f);
                if (o16) ((__hip_bfloat16*)out)[(size_t)orow * NOUT + col] = (__hip_bfloat16)v;
                else     ((float*)out)[(size_t)orow * NOUT + col] = v;
            }
        }
    }
}

// ---------- launch ----------
extern "C" void kernel_launch(void* const* d_in, const int* in_sizes, int n_in,
                              void* d_out, int out_size, void* d_ws, size_t ws_size,
                              hipStream_t stream) {
    const void* x   = d_in[0];
    const int* eidx = (const int*)d_in[1];
    const void* W1l = d_in[2];
    const void* b1  = d_in[3];
    const void* W1r = d_in[4];
    const void* W2l = d_in[5];
    const void* b2  = d_in[6];
    const void* W2r = d_in[7];

    const int N = in_sizes[0] / D_FEAT;   // 50000
    const int E = in_sizes[1] / 2;        // 600000
    const int* src = eidx;                // [2, E] row-major (proven R5)
    const int* dst = eidx + E;

    char* ws = (char*)d_ws;
    size_t o = 0;
    auto alloc = [&](size_t bytes) -> void* {
        void* p = ws + o;
        o += (bytes + 255) & ~(size_t)255;
        return p;
    };
    int* flags  = (int*)alloc(256);
    int* deg    = (int*)alloc((size_t)N * 4);
    int* off    = (int*)alloc((size_t)(N + 1) * 4);
    int* cursor = (int*)alloc((size_t)N * 4);
    int* esrc   = (int*)alloc((size_t)E * 4);
    unsigned short* wconv = (unsigned short*)alloc(49344 * 2);
    __hip_bfloat16* h = (__hip_bfloat16*)alloc((size_t)N * D_FEAT * 2);
    size_t base_need = o;                                   // ~15.9 MB
    unsigned short* xb = (unsigned short*)alloc((size_t)N * D_FEAT * 2);
    const bool use_xb = (o <= ws_size);                     // ~28.7 MB total
    (void)n_in; (void)out_size; (void)base_need;

    probe_kernel<<<1, 64, 0, stream>>>(x, flags);
    prep_kernel<<<1, 256, 0, stream>>>(W1l, b1, W1r, W2l, b2, W2r, flags, wconv);
    hipMemsetAsync(deg, 0, (size_t)N * 4, stream);
    count_deg_kernel<<<(E + 255) / 256, 256, 0, stream>>>(dst, deg, E);
    scan_kernel<<<1, 256, 0, stream>>>(deg, off, cursor, N);
    fill_kernel<<<(E + 255) / 256, 256, 0, stream>>>(src, dst, cursor, esrc, E);

    const void* feat1;
    const int* flag1;
    if (use_xb) {
        const int n4 = N * D_FEAT / 4;
        conv_kernel<<<(n4 + 255) / 256, 256, 0, stream>>>(x, flags, xb, n4);
        feat1 = xb; flag1 = flags + 1;    // xb is always bf16
    } else {
        feat1 = x; flag1 = flags + 0;     // fall back to direct reads
    }

    const int nblocks = (N + 63) / 64;
    // layer 1: h = relu(sage(x)); h always bf16
    fused_layer_kernel<128, true><<<nblocks, 256, 0, stream>>>(
        feat1, flag1, off, esrc,
        wconv + 0, wconv + 16384, wconv + 49152, flags + 1, h, N);
    // layer 2: out = sage(h); out dtype follows probed scenario
    fused_layer_kernel<64, false><<<nblocks, 256, 0, stream>>>(
        h, flags + 1, off, esrc,
        wconv + 32768, wconv + 40960, wconv + 49280, flags + 0, d_out, N);
}

// Round 7
// 274.537 us; speedup vs baseline: 1.8023x; 1.4649x over previous
//
#include <hip/hip_runtime.h>
#include <hip/hip_bf16.h>

typedef __bf16 bf16x8 __attribute__((ext_vector_type(8)));
typedef float f32x4 __attribute__((ext_vector_type(4)));

#define D_FEAT 128
#define MT_STRIDE 136   // 128 + 8 pad (ushort units); row stride 272 B, 16B-aligned
#define CHUNK 1024

__device__ __forceinline__ float bf16_to_f(unsigned int u16) {
    union { unsigned int i; float f; } c; c.i = u16 << 16; return c.f;
}
__device__ __forceinline__ unsigned short f_to_bf16(float f) {
    __hip_bfloat16 h = (__hip_bfloat16)f;
    return *(unsigned short*)&h;
}
__device__ __forceinline__ float ld(const void* p, int is16, size_t i) {
    return is16 ? (float)((const __hip_bfloat16*)p)[i] : ((const float*)p)[i];
}

// ---------- dtype probe (proven R5/R6) ----------
__global__ void probe_kernel(const void* x, int* flags) {
    if (threadIdx.x < 64) {
        const unsigned short* u = (const unsigned short*)x;
        unsigned short v = u[threadIdx.x * 2];
        int e = (v >> 7) & 0xFF;
        bool plaus = (e >= 100 && e <= 140);
        unsigned long long m = __ballot(plaus);
        if (threadIdx.x == 0) {
            flags[0] = (__popcll(m) >= 48) ? 1 : 0;  // 1: tensors bf16, 0: fp32
            flags[1] = 1;                            // internal bufs always bf16
        }
    }
}

// ---------- weight pack -> bf16, multi-block (was 84 us serial!) ----------
// u16 layout: W1l@0[16384] W1r@16384[16384] W2l@32768[8192] W2r@40960[8192]
//             b1@49152[128] b2@49280[64]   total 49344
__global__ void prep_kernel(const void* W1l, const void* b1, const void* W1r,
                            const void* W2l, const void* b2, const void* W2r,
                            const int* __restrict__ flags, unsigned short* wout) {
    int i = blockIdx.x * blockDim.x + threadIdx.x;
    if (i >= 49344) return;
    const int is16 = flags[0];
    const void* s; int base;
    if      (i < 16384) { s = W1l; base = 0; }
    else if (i < 32768) { s = W1r; base = 16384; }
    else if (i < 40960) { s = W2l; base = 32768; }
    else if (i < 49152) { s = W2r; base = 40960; }
    else if (i < 49280) { s = b1;  base = 49152; }
    else                { s = b2;  base = 49280; }
    wout[i] = f_to_bf16(ld(s, is16, i - base));
}

// ---------- x -> bf16 conversion (or copy) ----------
__global__ void conv_kernel(const void* x, const int* __restrict__ flags,
                            unsigned short* __restrict__ xb, int n4) {
    int i = blockIdx.x * blockDim.x + threadIdx.x;
    if (i >= n4) return;
    if (flags[0]) {
        ((uint2*)xb)[i] = ((const uint2*)x)[i];
    } else {
        const float4 v = ((const float4*)x)[i];
        union { unsigned short us[4]; uint2 u; } t;
        t.us[0] = f_to_bf16(v.x); t.us[1] = f_to_bf16(v.y);
        t.us[2] = f_to_bf16(v.z); t.us[3] = f_to_bf16(v.w);
        ((uint2*)xb)[i] = t.u;
    }
}

// ---------- CSR construction ----------
__global__ void count_deg_kernel(const int* __restrict__ dst, int* __restrict__ deg, int E) {
    int i = blockIdx.x * blockDim.x + threadIdx.x;
    if (i < E) atomicAdd(&deg[dst[i]], 1);
}

// multi-block scan, phase 1: per-chunk sums
__global__ void scan1_kernel(const int* __restrict__ deg, int* __restrict__ bsum, int n) {
    __shared__ int ws[4];
    const int lane = threadIdx.x & 63, wv = threadIdx.x >> 6;
    int i0 = blockIdx.x * CHUNK + threadIdx.x * 4;
    int s = 0;
    #pragma unroll
    for (int j = 0; j < 4; ++j) if (i0 + j < n) s += deg[i0 + j];
    #pragma unroll
    for (int d = 1; d < 64; d <<= 1) s += __shfl_xor(s, d, 64);
    if (lane == 0) ws[wv] = s;
    __syncthreads();
    if (threadIdx.x == 0) bsum[blockIdx.x] = ws[0] + ws[1] + ws[2] + ws[3];
}

// phase 2: exclusive scan of <=64 chunk sums (one wave)
__global__ void scan2_kernel(int* __restrict__ bsum, int nb) {
    int lane = threadIdx.x;
    int v = (lane < nb) ? bsum[lane] : 0;
    int sc = v;
    #pragma unroll
    for (int s = 1; s < 64; s <<= 1) {
        int t = __shfl_up(sc, s, 64);
        if (lane >= s) sc += t;
    }
    if (lane < nb) bsum[lane] = sc - v;
}

// phase 3: chunk-local exclusive scan + chunk base; write off & cursor (+sentinel)
__global__ void scan3_kernel(const int* __restrict__ deg, const int* __restrict__ bsum,
                             int* __restrict__ off, int* __restrict__ cursor, int n, int E) {
    __shared__ int ws[4];
    const int lane = threadIdx.x & 63, wv = threadIdx.x >> 6;
    int i0 = blockIdx.x * CHUNK + threadIdx.x * 4;
    int v0 = (i0 + 0 < n) ? deg[i0 + 0] : 0;
    int v1 = (i0 + 1 < n) ? deg[i0 + 1] : 0;
    int v2 = (i0 + 2 < n) ? deg[i0 + 2] : 0;
    int v3 = (i0 + 3 < n) ? deg[i0 + 3] : 0;
    int tsum = v0 + v1 + v2 + v3;
    int sc = tsum;
    #pragma unroll
    for (int s = 1; s < 64; s <<= 1) {
        int t = __shfl_up(sc, s, 64);
        if (lane >= s) sc += t;
    }
    if (lane == 63) ws[wv] = sc;
    __syncthreads();
    int woff = 0;
    for (int w = 0; w < wv; ++w) woff += ws[w];
    int p = bsum[blockIdx.x] + woff + (sc - tsum);
    if (i0 + 0 < n) { off[i0 + 0] = p; cursor[i0 + 0] = p; p += v0; }
    if (i0 + 1 < n) { off[i0 + 1] = p; cursor[i0 + 1] = p; p += v1; }
    if (i0 + 2 < n) { off[i0 + 2] = p; cursor[i0 + 2] = p; p += v2; }
    if (i0 + 3 < n) { off[i0 + 3] = p; cursor[i0 + 3] = p; p += v3; }
    if (blockIdx.x == 0 && threadIdx.x == 0) off[n] = E;   // sentinel
}

__global__ void fill_kernel(const int* __restrict__ src, const int* __restrict__ dst,
                            int* __restrict__ cursor, int* __restrict__ esrc, int E) {
    int i = blockIdx.x * blockDim.x + threadIdx.x;
    if (i < E) {
        int p = atomicAdd(&cursor[dst[i]], 1);
        esrc[p] = src[i];
    }
}

// ---------- fused layer v2: 512 threads / 8 waves per 64-node block ----------
// Agg: wave owns 8 nodes (contiguous CSR segment), 8-wide edge stream.
// GEMM: 16-row tile split column-wise between wave pairs (all 8 waves compute).
template <int NOUT, bool RELU>
__global__ __launch_bounds__(512)
void fused_layer_kernel(const void* feat, const int* __restrict__ flagp,
                        const int* __restrict__ off, const int* __restrict__ esrc,
                        const unsigned short* __restrict__ Wl,
                        const unsigned short* __restrict__ Wr,
                        const unsigned short* __restrict__ bias,
                        const int* __restrict__ oflag,
                        void* __restrict__ out, int N) {
    __shared__ unsigned short meanT[64][MT_STRIDE];
    const int tid = threadIdx.x;
    const int lane = tid & 63;
    const int wave = tid >> 6;          // 0..7
    const int is16 = flagp[0];          // wave-uniform
    const int o16 = oflag[0];
    const int node0 = blockIdx.x * 64;

    // ---- phase 1: aggregation, 8 nodes per wave ----
    const int a_lo = node0 + wave * 8;
    if (a_lo < N) {
        const int a_hi = min(a_lo + 8, N);
        int offv = off[min(a_lo + min(lane, 8), N)];
        #define OFFAT(i) __shfl(offv, (i), 64)
        const int e_end = OFFAT(a_hi - a_lo);
        int e = OFFAT(0);
        int g = a_lo;
        int gstart = e;
        int gend = OFFAT(1);
        float ax = 0.f, ay = 0.f;       // lane covers features 2*lane, 2*lane+1
        for (; e < e_end; e += 8) {
            int sk[8];
            #pragma unroll
            for (int k = 0; k < 8; ++k) sk[k] = esrc[min(e + k, e_end - 1)];
            float rx[8], ry[8];
            if (is16) {
                #pragma unroll
                for (int k = 0; k < 8; ++k) {
                    unsigned int u = ((const unsigned int*)
                        ((const unsigned short*)feat + (size_t)sk[k] * D_FEAT))[lane];
                    rx[k] = bf16_to_f(u & 0xffffu);
                    ry[k] = bf16_to_f(u >> 16);
                }
            } else {
                #pragma unroll
                for (int k = 0; k < 8; ++k) {
                    float2 v = ((const float2*)
                        ((const float*)feat + (size_t)sk[k] * D_FEAT))[lane];
                    rx[k] = v.x; ry[k] = v.y;
                }
            }
            #pragma unroll
            for (int k = 0; k < 8; ++k) {
                if (e + k < e_end) {
                    while (e + k >= gend) {     // wave-uniform flush of node g
                        int d = gend - gstart;
                        float inv = 1.f / (float)(d > 0 ? d : 1);
                        unsigned int pk = (unsigned int)f_to_bf16(ax * inv)
                                        | ((unsigned int)f_to_bf16(ay * inv) << 16);
                        *(unsigned int*)&meanT[g - node0][lane * 2] = pk;
                        ax = ay = 0.f;
                        ++g; gstart = gend;
                        gend = OFFAT(min(g - a_lo + 1, 8));
                    }
                    ax += rx[k]; ay += ry[k];
                }
            }
        }
        while (g < a_hi) {                      // tail flush
            int d = gend - gstart;
            float inv = 1.f / (float)(d > 0 ? d : 1);
            unsigned int pk = (unsigned int)f_to_bf16(ax * inv)
                            | ((unsigned int)f_to_bf16(ay * inv) << 16);
            *(unsigned int*)&meanT[g - node0][lane * 2] = pk;
            ax = ay = 0.f;
            ++g; gstart = gend;
            gend = OFFAT(min(g - a_lo + 1, 8));
        }
        #undef OFFAT
    }
    __syncthreads();

    // ---- phase 2: dual GEMM; wave pair (rowg, colh) ----
    const int rowg = wave >> 1;     // 16-row tile 0..3
    const int colh = wave & 1;      // column half
    constexpr int NT = NOUT / 32;   // 16-col tiles per wave
    const int n_lo = node0 + rowg * 16;
    const int lrow = lane & 15;
    const int kg = lane >> 4;
    f32x4 acc[NT];
    #pragma unroll
    for (int t = 0; t < NT; ++t) acc[t] = (f32x4){0.f, 0.f, 0.f, 0.f};

    const int grow = min(n_lo + lrow, N - 1);
    #pragma unroll
    for (int hh = 0; hh < 2; ++hh) {
        const unsigned short* W = hh ? Wr : Wl;
        #pragma unroll
        for (int ks = 0; ks < 4; ++ks) {
            const int k0 = ks * 32 + kg * 8;
            bf16x8 a;
            if (hh == 0) {
                a = *(const bf16x8*)&meanT[rowg * 16 + lrow][k0];
            } else if (is16) {
                a = *(const bf16x8*)((const unsigned short*)feat + (size_t)grow * D_FEAT + k0);
            } else {
                const float* fp = (const float*)feat + (size_t)grow * D_FEAT + k0;
                union { bf16x8 v; unsigned short us[8]; } t;
                #pragma unroll
                for (int j = 0; j < 8; ++j) t.us[j] = f_to_bf16(fp[j]);
                a = t.v;
            }
            #pragma unroll
            for (int t = 0; t < NT; ++t) {
                int col16 = colh * NT + t;
                bf16x8 b = *(const bf16x8*)(W + (size_t)(col16 * 16 + lrow) * D_FEAT + k0);
                acc[t] = __builtin_amdgcn_mfma_f32_16x16x32_bf16(a, b, acc[t], 0, 0, 0);
            }
        }
    }
    // C/D: col = lane&15, row = (lane>>4)*4 + reg  [m89/m91]
    const int orow0 = n_lo + kg * 4;
    #pragma unroll
    for (int t = 0; t < NT; ++t) {
        const int col = (colh * NT + t) * 16 + lrow;
        float bv = bf16_to_f(bias[col]);
        #pragma unroll
        for (int r = 0; r < 4; ++r) {
            int orow = orow0 + r;
            if (orow < N) {
                float v = acc[t][r] + bv;
                if (RELU) v = fmaxf(v, 0.f);
                if (o16) ((__hip_bfloat16*)out)[(size_t)orow * NOUT + col] = (__hip_bfloat16)v;
                else     ((float*)out)[(size_t)orow * NOUT + col] = v;
            }
        }
    }
}

// ---------- launch ----------
extern "C" void kernel_launch(void* const* d_in, const int* in_sizes, int n_in,
                              void* d_out, int out_size, void* d_ws, size_t ws_size,
                              hipStream_t stream) {
    const void* x   = d_in[0];
    const int* eidx = (const int*)d_in[1];
    const void* W1l = d_in[2];
    const void* b1  = d_in[3];
    const void* W1r = d_in[4];
    const void* W2l = d_in[5];
    const void* b2  = d_in[6];
    const void* W2r = d_in[7];

    const int N = in_sizes[0] / D_FEAT;   // 50000
    const int E = in_sizes[1] / 2;        // 600000
    const int* src = eidx;                // [2, E] row-major (proven R5)
    const int* dst = eidx + E;

    char* ws = (char*)d_ws;
    size_t o = 0;
    auto alloc = [&](size_t bytes) -> void* {
        void* p = ws + o;
        o += (bytes + 255) & ~(size_t)255;
        return p;
    };
    int* flags  = (int*)alloc(256);
    int* bsum   = (int*)alloc(64 * 4);
    int* deg    = (int*)alloc((size_t)N * 4);
    int* off    = (int*)alloc((size_t)(N + 1) * 4);
    int* cursor = (int*)alloc((size_t)N * 4);
    int* esrc   = (int*)alloc((size_t)E * 4);
    unsigned short* wconv = (unsigned short*)alloc(49344 * 2);
    __hip_bfloat16* h = (__hip_bfloat16*)alloc((size_t)N * D_FEAT * 2);
    unsigned short* xb = (unsigned short*)alloc((size_t)N * D_FEAT * 2);
    const bool use_xb = (o <= ws_size);   // ~28.7 MB; proven available in R6
    (void)n_in; (void)out_size;

    probe_kernel<<<1, 64, 0, stream>>>(x, flags);
    prep_kernel<<<(49344 + 255) / 256, 256, 0, stream>>>(W1l, b1, W1r, W2l, b2, W2r, flags, wconv);
    hipMemsetAsync(deg, 0, (size_t)N * 4, stream);
    count_deg_kernel<<<(E + 255) / 256, 256, 0, stream>>>(dst, deg, E);
    const int nchunk = (N + CHUNK - 1) / CHUNK;   // 49 <= 64
    scan1_kernel<<<nchunk, 256, 0, stream>>>(deg, bsum, N);
    scan2_kernel<<<1, 64, 0, stream>>>(bsum, nchunk);
    scan3_kernel<<<nchunk, 256, 0, stream>>>(deg, bsum, off, cursor, N, E);
    fill_kernel<<<(E + 255) / 256, 256, 0, stream>>>(src, dst, cursor, esrc, E);

    const void* feat1;
    const int* flag1;
    if (use_xb) {
        const int n4 = N * D_FEAT / 4;
        conv_kernel<<<(n4 + 255) / 256, 256, 0, stream>>>(x, flags, xb, n4);
        feat1 = xb; flag1 = flags + 1;    // xb always bf16
    } else {
        feat1 = x; flag1 = flags + 0;
    }

    const int nblocks = (N + 63) / 64;
    // layer 1: h = relu(sage(x)); h always bf16
    fused_layer_kernel<128, true><<<nblocks, 512, 0, stream>>>(
        feat1, flag1, off, esrc,
        wconv + 0, wconv + 16384, wconv + 49152, flags + 1, h, N);
    // layer 2: out = sage(h); out dtype follows probed scenario
    fused_layer_kernel<64, false><<<nblocks, 512, 0, stream>>>(
        h, flags + 1, off, esrc,
        wconv + 32768, wconv + 40960, wconv + 49280, flags + 0, d_out, N);
}

// Round 8
// 249.614 us; speedup vs baseline: 1.9823x; 1.0998x over previous
//
#include <hip/hip_runtime.h>
#include <hip/hip_bf16.h>

typedef __bf16 bf16x8 __attribute__((ext_vector_type(8)));
typedef float f32x4 __attribute__((ext_vector_type(4)));

#define D_FEAT 128
#define MT_STRIDE 136   // 128 + 8 pad (ushort units); row stride 272 B
#define CHUNK 1024

__device__ __forceinline__ float bits_to_f(unsigned int u) {
    union { unsigned int i; float f; } c; c.i = u; return c.f;
}
__device__ __forceinline__ unsigned short f_to_bf16(float f) {
    __hip_bfloat16 h = (__hip_bfloat16)f;
    return *(unsigned short*)&h;
}
__device__ __forceinline__ float ld(const void* p, int is16, size_t i) {
    return is16 ? (float)((const __hip_bfloat16*)p)[i] : ((const float*)p)[i];
}

// ---------- dtype probe (proven R5-R7) ----------
__global__ void probe_kernel(const void* x, int* flags) {
    if (threadIdx.x < 64) {
        const unsigned short* u = (const unsigned short*)x;
        unsigned short v = u[threadIdx.x * 2];
        int e = (v >> 7) & 0xFF;
        bool plaus = (e >= 100 && e <= 140);
        unsigned long long m = __ballot(plaus);
        if (threadIdx.x == 0) {
            flags[0] = (__popcll(m) >= 48) ? 1 : 0;  // 1: bf16 tensors, 0: fp32
            flags[1] = 1;                            // internal bufs always bf16
        }
    }
}

// ---------- weight pack -> bf16 ----------
// u16 layout: W1l@0[16384] W1r@16384[16384] W2l@32768[8192] W2r@40960[8192]
//             b1@49152[128] b2@49280[64]
__global__ void prep_kernel(const void* W1l, const void* b1, const void* W1r,
                            const void* W2l, const void* b2, const void* W2r,
                            const int* __restrict__ flags, unsigned short* wout) {
    int i = blockIdx.x * blockDim.x + threadIdx.x;
    if (i >= 49344) return;
    const int is16 = flags[0];
    const void* s; int base;
    if      (i < 16384) { s = W1l; base = 0; }
    else if (i < 32768) { s = W1r; base = 16384; }
    else if (i < 40960) { s = W2l; base = 32768; }
    else if (i < 49152) { s = W2r; base = 40960; }
    else if (i < 49280) { s = b1;  base = 49152; }
    else                { s = b2;  base = 49280; }
    wout[i] = f_to_bf16(ld(s, is16, i - base));
}

// ---------- x -> bf16 (or copy) ----------
__global__ void conv_kernel(const void* x, const int* __restrict__ flags,
                            unsigned short* __restrict__ xb, int n4) {
    int i = blockIdx.x * blockDim.x + threadIdx.x;
    if (i >= n4) return;
    if (flags[0]) {
        ((uint2*)xb)[i] = ((const uint2*)x)[i];
    } else {
        const float4 v = ((const float4*)x)[i];
        union { unsigned short us[4]; uint2 u; } t;
        t.us[0] = f_to_bf16(v.x); t.us[1] = f_to_bf16(v.y);
        t.us[2] = f_to_bf16(v.z); t.us[3] = f_to_bf16(v.w);
        ((uint2*)xb)[i] = t.u;
    }
}

// zero row N of xb and h (dummy-edge target)
__global__ void zero_rows_kernel(unsigned short* xb, unsigned short* h, int N) {
    int t = threadIdx.x;   // 128
    xb[(size_t)N * D_FEAT + t] = 0;
    h[(size_t)N * D_FEAT + t] = 0;
}

// ---------- CSR construction (padded to multiples of 4 per node) ----------
__global__ void count_deg_kernel(const int* __restrict__ dst, int* __restrict__ deg, int E) {
    int i = blockIdx.x * blockDim.x + threadIdx.x;
    if (i < E) atomicAdd(&deg[dst[i]], 1);
}

__global__ void scan1_kernel(const int* __restrict__ deg, int* __restrict__ bsum, int n) {
    __shared__ int ws[4];
    const int lane = threadIdx.x & 63, wv = threadIdx.x >> 6;
    int i0 = blockIdx.x * CHUNK + threadIdx.x * 4;
    int s = 0;
    #pragma unroll
    for (int j = 0; j < 4; ++j)
        if (i0 + j < n) { int d = deg[i0 + j]; s += (d + 3) & ~3; }
    #pragma unroll
    for (int d = 1; d < 64; d <<= 1) s += __shfl_xor(s, d, 64);
    if (lane == 0) ws[wv] = s;
    __syncthreads();
    if (threadIdx.x == 0) bsum[blockIdx.x] = ws[0] + ws[1] + ws[2] + ws[3];
}

__global__ void scan2_kernel(int* __restrict__ bsum, int nb, int* __restrict__ off, int n) {
    int lane = threadIdx.x;
    int v = (lane < nb) ? bsum[lane] : 0;
    int sc = v;
    #pragma unroll
    for (int s = 1; s < 64; s <<= 1) {
        int t = __shfl_up(sc, s, 64);
        if (lane >= s) sc += t;
    }
    if (lane == nb - 1) off[n] = sc;        // sentinel: total padded edges
    if (lane < nb) bsum[lane] = sc - v;
}

__global__ void scan3_kernel(const int* __restrict__ deg, const int* __restrict__ bsum,
                             int* __restrict__ off, int* __restrict__ cursor, int n) {
    __shared__ int ws[4];
    const int lane = threadIdx.x & 63, wv = threadIdx.x >> 6;
    int i0 = blockIdx.x * CHUNK + threadIdx.x * 4;
    int v0 = 0, v1 = 0, v2 = 0, v3 = 0;
    if (i0 + 0 < n) v0 = (deg[i0 + 0] + 3) & ~3;
    if (i0 + 1 < n) v1 = (deg[i0 + 1] + 3) & ~3;
    if (i0 + 2 < n) v2 = (deg[i0 + 2] + 3) & ~3;
    if (i0 + 3 < n) v3 = (deg[i0 + 3] + 3) & ~3;
    int tsum = v0 + v1 + v2 + v3;
    int sc = tsum;
    #pragma unroll
    for (int s = 1; s < 64; s <<= 1) {
        int t = __shfl_up(sc, s, 64);
        if (lane >= s) sc += t;
    }
    if (lane == 63) ws[wv] = sc;
    __syncthreads();
    int woff = 0;
    for (int w = 0; w < wv; ++w) woff += ws[w];
    int p = bsum[blockIdx.x] + woff + (sc - tsum);
    if (i0 + 0 < n) { off[i0 + 0] = p; cursor[i0 + 0] = p; p += v0; }
    if (i0 + 1 < n) { off[i0 + 1] = p; cursor[i0 + 1] = p; p += v1; }
    if (i0 + 2 < n) { off[i0 + 2] = p; cursor[i0 + 2] = p; p += v2; }
    if (i0 + 3 < n) { off[i0 + 3] = p; cursor[i0 + 3] = p; p += v3; }
}

__global__ void fill_kernel(const int* __restrict__ src, const int* __restrict__ dst,
                            int* __restrict__ cursor, int* __restrict__ esrc, int E) {
    int i = blockIdx.x * blockDim.x + threadIdx.x;
    if (i < E) {
        int p = atomicAdd(&cursor[dst[i]], 1);
        esrc[p] = src[i];
    }
}

// pad each node's segment to multiple of 4 with dummy edges -> zero row N
__global__ void fillpad_kernel(const int* __restrict__ off, const int* __restrict__ deg,
                               int* __restrict__ esrc, int N) {
    int g = blockIdx.x * blockDim.x + threadIdx.x;
    if (g >= N) return;
    int s = off[g] + deg[g];
    int e = off[g] + ((deg[g] + 3) & ~3);
    for (int i = s; i < e; ++i) esrc[i] = N;
}

// ---------- fused layer v3: quad-row gathers + dual MFMA GEMM ----------
// 256 thr / 4 waves / 32 nodes per block. Wave owns 8 nodes (padded CSR segment).
// Gather: 16 lanes/row x 16B -> one dwordx4 instr = 4 rows; 8 in flight = 32 edges.
template <int NOUT, bool RELU>
__global__ __launch_bounds__(256)
void fused_layer_kernel(const unsigned short* __restrict__ feat,  // (N+1) rows, row N = 0
                        const int* __restrict__ off, const int* __restrict__ deg,
                        const int* __restrict__ esrc,
                        const unsigned short* __restrict__ Wl,
                        const unsigned short* __restrict__ Wr,
                        const unsigned short* __restrict__ bias,
                        const int* __restrict__ oflag,
                        void* __restrict__ out, int N) {
    __shared__ unsigned short meanT[32][MT_STRIDE];
    const int tid = threadIdx.x;
    const int lane = tid & 63;
    const int wave = tid >> 6;       // 0..3
    const int node0 = blockIdx.x * 32;
    const int o16 = oflag[0];

    const int a_lo = node0 + wave * 8;
    if (a_lo < N) {
        const int a_hi = min(a_lo + 8, N);
        const int nn = a_hi - a_lo;
        int offv = off[min(a_lo + min(lane, 8), N)];
        int degv = deg[min(a_lo + min(lane, 7), N - 1)];
        #define OFFAT(i) __shfl(offv, (i), 64)
        const int e_beg = OFFAT(0);
        const int e_end = OFFAT(nn);
        const int quarter = lane >> 4;   // which row of the quartet
        const int fl = lane & 15;        // features 8*fl .. 8*fl+7
        float ax[8];
        #pragma unroll
        for (int i = 0; i < 8; ++i) ax[i] = 0.f;
        int g = a_lo;
        int gend = OFFAT(1);

        auto flush = [&](int gg) {
            int td = __shfl(degv, gg - a_lo, 64);
            float inv = 1.f / (float)(td > 0 ? td : 1);
            unsigned int pk[4];
            #pragma unroll
            for (int i = 0; i < 4; ++i) {
                float v0 = ax[2 * i], v1 = ax[2 * i + 1];
                v0 += __shfl_xor(v0, 16, 64); v0 += __shfl_xor(v0, 32, 64);
                v1 += __shfl_xor(v1, 16, 64); v1 += __shfl_xor(v1, 32, 64);
                pk[i] = (unsigned int)f_to_bf16(v0 * inv)
                      | ((unsigned int)f_to_bf16(v1 * inv) << 16);
                ax[2 * i] = 0.f; ax[2 * i + 1] = 0.f;
            }
            if (quarter == 0)
                *(uint4*)&meanT[gg - node0][fl * 8] = make_uint4(pk[0], pk[1], pk[2], pk[3]);
        };

        int cur = (e_beg < e_end) ? esrc[min(e_beg + (lane & 31), e_end - 1)] : 0;
        for (int e = e_beg; e < e_end; e += 32) {
            int nxt = (e + 32 < e_end) ? esrc[min(e + 32 + (lane & 31), e_end - 1)] : 0;
            uint4 r[8];
            #pragma unroll
            for (int k = 0; k < 8; ++k) {
                int sk = __shfl(cur, 4 * k + quarter, 64);
                r[k] = *(const uint4*)(feat + (size_t)sk * D_FEAT + fl * 8);
            }
            #pragma unroll
            for (int k = 0; k < 8; ++k) {
                const int eb = e + 4 * k;
                if (eb < e_end) {
                    while (eb >= gend) {          // wave-uniform node boundary
                        flush(g);
                        ++g;
                        gend = OFFAT(min(g - a_lo + 1, 8));
                    }
                    uint4 u = r[k];
                    ax[0] += bits_to_f(u.x << 16); ax[1] += bits_to_f(u.x & 0xffff0000u);
                    ax[2] += bits_to_f(u.y << 16); ax[3] += bits_to_f(u.y & 0xffff0000u);
                    ax[4] += bits_to_f(u.z << 16); ax[5] += bits_to_f(u.z & 0xffff0000u);
                    ax[6] += bits_to_f(u.w << 16); ax[7] += bits_to_f(u.w & 0xffff0000u);
                }
            }
            cur = nxt;
        }
        while (g < a_hi) {                        // tail flush
            flush(g);
            ++g;
            gend = OFFAT(min(g - a_lo + 1, 8));
        }
        #undef OFFAT
    }
    __syncthreads();

    // ---- GEMM: wave (rowg, colh); 16 rows x NOUT/2 cols each ----
    const int rowg = wave >> 1;
    const int colh = wave & 1;
    constexpr int NT = NOUT / 32;
    const int n_lo = node0 + rowg * 16;
    const int lrow = lane & 15;
    const int kg = lane >> 4;
    f32x4 acc[NT];
    #pragma unroll
    for (int t = 0; t < NT; ++t) acc[t] = (f32x4){0.f, 0.f, 0.f, 0.f};

    const int grow = min(n_lo + lrow, N);   // row N = zeros
    #pragma unroll
    for (int hh = 0; hh < 2; ++hh) {
        const unsigned short* W = hh ? Wr : Wl;
        #pragma unroll
        for (int ks = 0; ks < 4; ++ks) {
            const int k0 = ks * 32 + kg * 8;
            bf16x8 a;
            if (hh == 0) a = *(const bf16x8*)&meanT[rowg * 16 + lrow][k0];
            else         a = *(const bf16x8*)(feat + (size_t)grow * D_FEAT + k0);
            #pragma unroll
            for (int t = 0; t < NT; ++t) {
                int col16 = colh * NT + t;
                bf16x8 b = *(const bf16x8*)(W + (size_t)(col16 * 16 + lrow) * D_FEAT + k0);
                acc[t] = __builtin_amdgcn_mfma_f32_16x16x32_bf16(a, b, acc[t], 0, 0, 0);
            }
        }
    }
    // C/D: col = lane&15, row = (lane>>4)*4 + reg  [m89/m91]
    const int orow0 = n_lo + kg * 4;
    #pragma unroll
    for (int t = 0; t < NT; ++t) {
        const int col = (colh * NT + t) * 16 + lrow;
        float bv = bits_to_f((unsigned int)bias[col] << 16);
        #pragma unroll
        for (int r2 = 0; r2 < 4; ++r2) {
            int orow = orow0 + r2;
            if (orow < N) {
                float v = acc[t][r2] + bv;
                if (RELU) v = fmaxf(v, 0.f);
                if (o16) ((__hip_bfloat16*)out)[(size_t)orow * NOUT + col] = (__hip_bfloat16)v;
                else     ((float*)out)[(size_t)orow * NOUT + col] = v;
            }
        }
    }
}

// ---------- launch ----------
extern "C" void kernel_launch(void* const* d_in, const int* in_sizes, int n_in,
                              void* d_out, int out_size, void* d_ws, size_t ws_size,
                              hipStream_t stream) {
    const void* x   = d_in[0];
    const int* eidx = (const int*)d_in[1];
    const void* W1l = d_in[2];
    const void* b1  = d_in[3];
    const void* W1r = d_in[4];
    const void* W2l = d_in[5];
    const void* b2  = d_in[6];
    const void* W2r = d_in[7];

    const int N = in_sizes[0] / D_FEAT;   // 50000
    const int E = in_sizes[1] / 2;        // 600000
    const int* src = eidx;                // [2, E] row-major (proven R5)
    const int* dst = eidx + E;

    char* ws = (char*)d_ws;
    size_t o = 0;
    auto alloc = [&](size_t bytes) -> void* {
        void* p = ws + o;
        o += (bytes + 255) & ~(size_t)255;
        return p;
    };
    int* flags  = (int*)alloc(256);
    int* bsum   = (int*)alloc(64 * 4);
    int* deg    = (int*)alloc((size_t)N * 4);
    int* off    = (int*)alloc((size_t)(N + 1) * 4);
    int* cursor = (int*)alloc((size_t)N * 4);
    int* esrc   = (int*)alloc((size_t)(E + 3 * N + 64) * 4);   // padded CSR
    unsigned short* wconv = (unsigned short*)alloc(49344 * 2);
    unsigned short* h  = (unsigned short*)alloc((size_t)(N + 1) * D_FEAT * 2);
    unsigned short* xb = (unsigned short*)alloc((size_t)(N + 1) * D_FEAT * 2);
    (void)n_in; (void)out_size; (void)ws_size;   // ~29.4 MB (28.7 proven R6/R7)

    probe_kernel<<<1, 64, 0, stream>>>(x, flags);
    prep_kernel<<<(49344 + 255) / 256, 256, 0, stream>>>(W1l, b1, W1r, W2l, b2, W2r, flags, wconv);
    hipMemsetAsync(deg, 0, (size_t)N * 4, stream);
    count_deg_kernel<<<(E + 255) / 256, 256, 0, stream>>>(dst, deg, E);
    const int nchunk = (N + CHUNK - 1) / CHUNK;   // 49 <= 64
    scan1_kernel<<<nchunk, 256, 0, stream>>>(deg, bsum, N);
    scan2_kernel<<<1, 64, 0, stream>>>(bsum, nchunk, off, N);
    scan3_kernel<<<nchunk, 256, 0, stream>>>(deg, bsum, off, cursor, N);
    fill_kernel<<<(E + 255) / 256, 256, 0, stream>>>(src, dst, cursor, esrc, E);
    fillpad_kernel<<<(N + 255) / 256, 256, 0, stream>>>(off, deg, esrc, N);

    const int n4 = N * D_FEAT / 4;
    conv_kernel<<<(n4 + 255) / 256, 256, 0, stream>>>(x, flags, xb, n4);
    zero_rows_kernel<<<1, 128, 0, stream>>>(xb, h, N);

    const int nblocks = (N + 31) / 32;
    // layer 1: h = relu(sage(xb)); h always bf16 (flags[1]==1)
    fused_layer_kernel<128, true><<<nblocks, 256, 0, stream>>>(
        xb, off, deg, esrc,
        wconv + 0, wconv + 16384, wconv + 49152, flags + 1, h, N);
    // layer 2: out = sage(h); out dtype follows probed scenario
    fused_layer_kernel<64, false><<<nblocks, 256, 0, stream>>>(
        h, off, deg, esrc,
        wconv + 32768, wconv + 40960, wconv + 49280, flags + 0, d_out, N);
}